// Round 9
// baseline (117.517 us; speedup 1.0000x reference)
//
#include <hip/hip_runtime.h>
#include <hip/hip_bf16.h>

// ---- problem constants -------------------------------------------------
#define IN_F   1024
#define OUT_F  1024
#define GS     5          // grid_size
#define SO     3          // spline_order
#define NB     (GS + SO)  // 8 basis functions per feature
#define NG     (GS + 2*SO + 1) // 12 grid points per feature row
#define BATCH  4096
#define KC     (IN_F + IN_F * NB)   // 9216 combined-K
#define BM 128
#define BN 128
#define BK 64
#define SPLITK 2
#define KPART  (KC / SPLITK)   // 4608
#define NT     (KPART / BK)    // 72 K-tiles per block

typedef __bf16 bf16x8 __attribute__((ext_vector_type(8)));
typedef float  f32x4  __attribute__((ext_vector_type(4)));

__device__ __forceinline__ void gload_lds16(const void* g, void* l) {
    __builtin_amdgcn_global_load_lds(
        (const __attribute__((address_space(1))) void*)g,
        (__attribute__((address_space(3))) void*)l,
        16, 0, 0);
}

// ---- fused prep: blocks [0,WC_BLK) build Wc, rest build A ---------------
#define WC_BLK 4608   // (131072 + 1048576) / 256
#define A_BLK  18432  // (524288 + 4194304) / 256

__global__ __launch_bounds__(256) void prep_all(const float* __restrict__ bw,
                                                const float* __restrict__ sw,
                                                const float* __restrict__ ss,
                                                const float* __restrict__ x,
                                                __bf16* __restrict__ W,
                                                __bf16* __restrict__ A) {
    if (blockIdx.x < WC_BLK) {
        const int t = blockIdx.x * 256 + threadIdx.x;
        const int NBASE = OUT_F * IN_F / 8;      // 131072 threads, 8 elems each
        if (t < NBASE) {
            const int o  = t >> 7;
            const int c8 = (t & 127) * 8;
            const float4* sp = (const float4*)(bw + (size_t)o * IN_F + c8);
            float4 v0 = sp[0], v1 = sp[1];
            float v[8] = {v0.x, v0.y, v0.z, v0.w, v1.x, v1.y, v1.z, v1.w};
            bf16x8 ov;
#pragma unroll
            for (int j = 0; j < 8; ++j) ov[j] = (__bf16)v[j];
            *(bf16x8*)(W + (size_t)o * KC + c8) = ov;
        } else {
            const int u = t - NBASE;             // one (o,f) pair per thread
            if (u >= OUT_F * IN_F) return;
            const int o = u >> 10, f = u & 1023;
            const float s = ss[(size_t)o * IN_F + f];
            const float4* sp = (const float4*)(sw + ((size_t)o * IN_F + f) * NB);
            float4 v0 = sp[0], v1 = sp[1];
            float v[8] = {v0.x, v0.y, v0.z, v0.w, v1.x, v1.y, v1.z, v1.w};
            bf16x8 ov;
#pragma unroll
            for (int j = 0; j < 8; ++j) ov[j] = (__bf16)(v[j] * s);
            *(bf16x8*)(W + (size_t)o * KC + IN_F + (size_t)f * NB) = ov;
        }
    } else {
        const int t = (blockIdx.x - WC_BLK) * 256 + threadIdx.x;
        const int NBASE = BATCH * IN_F / 8;      // silu: 8 elems/thread
        if (t < NBASE) {
            const int b  = t >> 7;
            const int c8 = (t & 127) * 8;
            const float4* sp = (const float4*)(x + (size_t)b * IN_F + c8);
            float4 v0 = sp[0], v1 = sp[1];
            float v[8] = {v0.x, v0.y, v0.z, v0.w, v1.x, v1.y, v1.z, v1.w};
            bf16x8 ov;
#pragma unroll
            for (int j = 0; j < 8; ++j) {
                float xx = v[j];
                ov[j] = (__bf16)(xx / (1.0f + __expf(-xx)));
            }
            *(bf16x8*)(A + (size_t)b * KC + c8) = ov;
        } else {
            const int u = t - NBASE;             // one (b,f) pair per thread
            if (u >= BATCH * IN_F) return;
            const int b = u >> 10, f = u & 1023;
            const float xv = x[(size_t)b * IN_F + f];
            const float h = 2.0f / GS;           // 0.4; uniform grid
            float gv[NG];
#pragma unroll
            for (int j = 0; j < NG; ++j) gv[j] = (float)(j - SO) * h - 1.0f;
            float bas[NB + SO];                  // 11 order-0 bases
#pragma unroll
            for (int j = 0; j < NB + SO; ++j)
                bas[j] = (xv >= gv[j] && xv < gv[j + 1]) ? 1.0f : 0.0f;
#pragma unroll
            for (int k = 1; k <= SO; ++k) {
                const float rk = 1.0f / ((float)k * h);   // constant-folded
#pragma unroll
                for (int j = 0; j <= (NB + SO - 1) - k; ++j) {
                    float left  = (xv - gv[j]) * rk;
                    float right = (gv[j + k + 1] - xv) * rk;
                    bas[j] = left * bas[j] + right * bas[j + 1];
                }
            }
            bf16x8 ov;
#pragma unroll
            for (int i = 0; i < NB; ++i) ov[i] = (__bf16)bas[i];
            *(bf16x8*)(A + (size_t)b * KC + IN_F + (size_t)f * NB) = ov;
        }
    }
}

// ---- zero-fill d_out (atomic-fallback path only) -----------------------
__global__ __launch_bounds__(256) void zero_out(float4* __restrict__ p, int n4) {
    const int i = blockIdx.x * 256 + threadIdx.x;
    if (i < n4) p[i] = float4{0.f, 0.f, 0.f, 0.f};
}

// ---- add split-K partial into d_out (ks=0 wrote d_out directly) --------
__global__ __launch_bounds__(256) void reduce_k(float4* __restrict__ C,
                                                const float4* __restrict__ P) {
    const size_t n4 = (size_t)BATCH * OUT_F / 4;   // 1,048,576
    for (size_t i = blockIdx.x * 256 + threadIdx.x; i < n4; i += 2048 * 256) {
        float4 c = C[i], p = P[i];
        c.x += p.x; c.y += p.y; c.z += p.z; c.w += p.w;
        C[i] = c;
    }
}

// ---- 128x128 GEMM, 4 waves, 2 BLOCKS/CU (the round's variable) ---------
// LDS 64 KB/block -> 2 co-resident blocks per CU: when one block drains a
// barrier/vmcnt, the other block's waves issue MFMA (m114 overlap). One
// barrier per K-tile; stage(kt+1) issued a full tile before its vmcnt(0)
// so the drain retires instantly. T2 swizzle (0 conflicts), T5 setprio.
#define MFMA_Q(AF, BF, NI0)                                                   \
    __builtin_amdgcn_s_setprio(1);                                            \
    _Pragma("unroll")                                                         \
    for (int kk_ = 0; kk_ < 2; ++kk_)                                         \
        _Pragma("unroll")                                                     \
        for (int i_ = 0; i_ < 4; ++i_)                                        \
            _Pragma("unroll")                                                 \
            for (int n_ = 0; n_ < 2; ++n_)                                    \
                acc[i_][(NI0) + n_] =                                         \
                    __builtin_amdgcn_mfma_f32_16x16x32_bf16(                  \
                        AF[i_][kk_], BF[n_][kk_], acc[i_][(NI0) + n_],        \
                        0, 0, 0);                                             \
    __builtin_amdgcn_s_setprio(0);

#define LGKM0_FENCE do {                                                      \
    asm volatile("s_waitcnt lgkmcnt(0)" ::: "memory");                        \
    __builtin_amdgcn_sched_barrier(0); } while (0)

template<bool ATOMIC>
__global__ __launch_bounds__(256, 2) void kan_gemm(const __bf16* __restrict__ A,
                                                   const __bf16* __restrict__ W,
                                                   float* __restrict__ C,
                                                   float* __restrict__ P) {
    __shared__ __bf16 sA[2][BM * BK];   // 2 x 16 KiB
    __shared__ __bf16 sB[2][BN * BK];   // 2 x 16 KiB

    const int tid  = threadIdx.x;
    const int gid  = blockIdx.x;
    // bijective XCD swizzle (512 = 8*64): XCD x owns one ks, two bn panels
    // (2.36 MB Wc -> L2-resident), all 32 bm.
    const int work = (gid & 7) * 64 + (gid >> 3);
    const int ks = work >> 8;          // 0..1
    const int bn = (work >> 5) & 7;    // 0..7
    const int bm = work & 31;          // 0..31

    const int lane = tid & 63;
    const int wv   = tid >> 6;         // 0..3
    const int wm   = wv >> 1;          // 0..1: M half
    const int wn   = wv & 1;           // 0..1: N half
    const int lr   = lane & 15;        // fragment row
    const int hi   = lane >> 4;        // 0..3: k-subslot
    const int key  = lr & 7;           // swizzle key (frag rows = 16*m + lr)

    const int slot0 = ((hi ^ key) << 3);        // kk=0 elem offset
    const int slot1 = (((4 + hi) ^ key) << 3);  // kk=1
    const int aBase = (wm * 64 + lr) * BK;
    const int bBase = (wn * 64 + lr) * BK;

    // staging map: 4 chunks/thread/matrix; 16 KB tile = 1024 16B chunks
    const __bf16* gA = A + (size_t)(bm * BM) * KC + ks * KPART;
    const __bf16* gW = W + (size_t)(bn * BN) * KC + ks * KPART;

    f32x4 acc[4][4] = {};
    bf16x8 af[4][2], bf01[2][2], bf23[2][2];

    auto stage = [&](int buf, int kt) {
#pragma unroll
        for (int p = 0; p < 4; ++p) {
            const int chunk = p * 256 + tid;
            const int row = chunk >> 3, slot = chunk & 7;
            const int col = (slot ^ (row & 7)) << 3;
            gload_lds16(gA + (size_t)row * KC + kt * BK + col,
                        &sA[buf][chunk * 8]);
        }
#pragma unroll
        for (int p = 0; p < 4; ++p) {
            const int chunk = p * 256 + tid;
            const int row = chunk >> 3, slot = chunk & 7;
            const int col = (slot ^ (row & 7)) << 3;
            gload_lds16(gW + (size_t)row * KC + kt * BK + col,
                        &sB[buf][chunk * 8]);
        }
    };

    // prologue: tile0 staged and drained (pays HBM latency once)
    stage(0, 0);
    asm volatile("s_waitcnt vmcnt(0)\n\ts_barrier" ::: "memory");

    for (int kt = 0; kt < NT; ++kt) {
        const int b = kt & 1;
        const __bf16* LA = &sA[b][0];
        const __bf16* LB = &sB[b][0];

        // ---- read A (8) + B01 (4); stage next tile into other buffer
#pragma unroll
        for (int i_ = 0; i_ < 4; ++i_) {
            af[i_][0] = *(const bf16x8*)&LA[aBase + i_ * (16 * BK) + slot0];
            af[i_][1] = *(const bf16x8*)&LA[aBase + i_ * (16 * BK) + slot1];
        }
#pragma unroll
        for (int n_ = 0; n_ < 2; ++n_) {
            bf01[n_][0] = *(const bf16x8*)&LB[bBase + n_ * (16 * BK) + slot0];
            bf01[n_][1] = *(const bf16x8*)&LB[bBase + n_ * (16 * BK) + slot1];
        }
        if (kt + 1 < NT) stage(b ^ 1, kt + 1);   // WAR-safe: b^1 readers
                                                  // passed boundary kt-1
        LGKM0_FENCE;
        MFMA_Q(af, bf01, 0);

        // ---- read B23 (4); second quadrant
#pragma unroll
        for (int n_ = 0; n_ < 2; ++n_) {
            bf23[n_][0] = *(const bf16x8*)&LB[bBase + (n_ + 2) * (16 * BK) + slot0];
            bf23[n_][1] = *(const bf16x8*)&LB[bBase + (n_ + 2) * (16 * BK) + slot1];
        }
        LGKM0_FENCE;
        MFMA_Q(af, bf23, 2);

        // ---- boundary: next tile resident (issued ~1 tile ago -> no stall)
        if (kt + 1 < NT)
            asm volatile("s_waitcnt vmcnt(0)\n\ts_barrier" ::: "memory");
    }

    // epilogue: C/D layout col=lane&15, row=hi*4+reg
    const int cr = hi * 4, cc = lane & 15;
    float* dst;
    if (ATOMIC) dst = C;
    else        dst = (ks == 0) ? C : P;
#pragma unroll
    for (int mi = 0; mi < 4; ++mi)
#pragma unroll
        for (int ni = 0; ni < 4; ++ni) {
            float* cp = dst + (size_t)(bm * BM + wm * 64 + mi * 16 + cr) * OUT_F
                            + bn * BN + wn * 64 + ni * 16 + cc;
#pragma unroll
            for (int r = 0; r < 4; ++r) {
                if (ATOMIC) unsafeAtomicAdd(cp + (size_t)r * OUT_F, acc[mi][ni][r]);
                else        cp[(size_t)r * OUT_F] = acc[mi][ni][r];
            }
        }
}

extern "C" void kernel_launch(void* const* d_in, const int* in_sizes, int n_in,
                              void* d_out, int out_size, void* d_ws, size_t ws_size,
                              hipStream_t stream) {
    const float* x    = (const float*)d_in[0];
    const float* bw   = (const float*)d_in[1];
    const float* sw   = (const float*)d_in[2];
    const float* ss   = (const float*)d_in[3];

    const size_t wc_bytes   = (size_t)OUT_F * KC * 2;          // 18,874,368
    const size_t a_bytes    = (size_t)BATCH * KC * 2;          // 75,497,472
    const size_t part_bytes = (size_t)BATCH * OUT_F * 4;       // 16,777,216
    if (ws_size < wc_bytes + a_bytes) return;

    __bf16* Wc = (__bf16*)d_ws;
    __bf16* A  = (__bf16*)((char*)d_ws + wc_bytes);
    float*  P  = (float*)((char*)d_ws + wc_bytes + a_bytes);

    prep_all<<<WC_BLK + A_BLK, 256, 0, stream>>>(bw, ss ? sw : sw, ss, x, Wc, A);

    const int grid = (BATCH / BM) * (OUT_F / BN) * SPLITK;     // 512
    if (ws_size >= wc_bytes + a_bytes + part_bytes) {
        kan_gemm<false><<<grid, 256, 0, stream>>>(A, Wc, (float*)d_out, P);
        reduce_k<<<2048, 256, 0, stream>>>((float4*)d_out, (const float4*)P);
    } else {
        const int n4 = BATCH * OUT_F / 4;
        zero_out<<<n4 / 256, 256, 0, stream>>>((float4*)d_out, n4);
        kan_gemm<true><<<grid, 256, 0, stream>>>(A, Wc, (float*)d_out, P);
    }
}